// Round 2
// baseline (28299.631 us; speedup 1.0000x reference)
//
#include <hip/hip_runtime.h>

// GeneratorDecoder: 128-step LSTM (H=32) + gumbel-argmax head (P=7), B=32768.
// 4 lanes per batch element, gate rows interleaved mod 4. Bit-identical FP
// trajectory to round-1 (same fmaf order, same reductions), restructured to
// eliminate register spills: h streamed in float4 chunks (k-chunk outer loop),
// outputs staged in LDS and flushed every 8 steps with coalesced float4 stores.

#define Hh 32
#define Pp 7
#define NDd 8
#define G4 128
#define WHH_S 40        // row stride: 8-bank skew between consecutive rows, 16B aligned
#define HBUF_S 36
#define OUT_S 56        // 8 steps * 7 floats, per-batch staging stride

// float-offset layout of the shared block (15872 floats = 63488 B)
#define OFF_WHH   0        // 128*40 = 5120
#define OFF_WIHB  5120     // 128*8  = 1024
#define OFF_WHEAD 6144     // 32*8   = 256
#define OFF_HBUF  6400     // 64*36  = 2304
#define OFF_OUTL  8704     // 64*56  = 3584   (aliased by W_init/b_init at setup)
#define OFF_OUTS  12288    // 64*56  = 3584
#define SMEM_F    15872
#define OFF_WINIT OFF_OUTL          // 32*40 = 1280 (init phase only)
#define OFF_BINIT (OFF_OUTL + 1280) // 32

__global__ __launch_bounds__(256, 2) void gen_decoder_kernel(
    const float* __restrict__ h_n, const float* __restrict__ c_n,
    const float* __restrict__ noise, const float* __restrict__ gumbel_u,
    const float* __restrict__ W_init, const float* __restrict__ b_init,
    const float* __restrict__ W_ih, const float* __restrict__ W_hh,
    const float* __restrict__ b_ih, const float* __restrict__ b_hh,
    const float* __restrict__ W_head, const float* __restrict__ b_head,
    const int* __restrict__ future_len, float* __restrict__ out, int B)
{
  __shared__ __align__(16) float sm[SMEM_F];

  const int tid = threadIdx.x;

  for (int i = tid; i < G4 * Hh; i += 256) {
    int r = i >> 5, k = i & 31;
    sm[OFF_WHH + r * WHH_S + k] = W_hh[i];
  }
  for (int i = tid; i < G4 * 8; i += 256) {
    int r = i >> 3, p = i & 7;
    sm[OFF_WIHB + i] = b_ih[r] + b_hh[r] + (p < 7 ? W_ih[r * 7 + p] : 0.f);
  }
  for (int i = tid; i < Hh * 8; i += 256) {
    int j = i >> 3, p = i & 7;
    sm[OFF_WHEAD + i] = (p < 7) ? W_head[p * Hh + j] : 0.f;
  }
  for (int i = tid; i < Hh * (Hh + NDd); i += 256) sm[OFF_WINIT + i] = W_init[i];
  if (tid < Hh) sm[OFF_BINIT + tid] = b_init[tid];
  __syncthreads();

  const int q  = tid & 3;
  const int bb = tid >> 2;
  const int b  = blockIdx.x * 64 + bb;
  const int T  = future_len[0];

  // ---- init: h0 = [h_n ; noise] @ W_init.T + b_init  (bit-identical order) ----
  {
    float x[Hh + NDd];
    const float4* hp = (const float4*)(h_n + (size_t)b * Hh);
#pragma unroll
    for (int i = 0; i < 8; i++) ((float4*)x)[i] = hp[i];
    const float4* nz = (const float4*)(noise + (size_t)b * NDd);
    ((float4*)x)[8] = nz[0];
    ((float4*)x)[9] = nz[1];
#pragma unroll
    for (int m = 0; m < 8; m++) {
      int j = q + 4 * m;
      float a = sm[OFF_BINIT + j];
      const float* wr = &sm[OFF_WINIT + j * (Hh + NDd)];
#pragma unroll
      for (int k = 0; k < Hh + NDd; k++) a = fmaf(wr[k], x[k], a);
      sm[OFF_HBUF + bb * HBUF_S + j] = a;
    }
  }
  float c[8];
#pragma unroll
  for (int m = 0; m < 8; m++) c[m] = c_n[(size_t)b * Hh + q + 4 * m];

  float bh[Pp];
#pragma unroll
  for (int p = 0; p < Pp; p++) bh[p] = b_head[p];

  // init phase used the OUT staging region for W_init -> barrier before reuse
  __syncthreads();

  int kcur = 7;  // y0 = 0 -> bias-only column
  const size_t strideT = (size_t)B * Pp;
  const float* gu = gumbel_u + (size_t)b * Pp;
  float* outL = out + (size_t)b * T * Pp;
  float* outS = out + (size_t)B * T * Pp + (size_t)b * T * Pp;

  for (int t = 0; t < T; ++t) {
    // gumbel inputs for this step (issue early)
    const float* ut = gu + (size_t)t * strideT;
    float u1 = ut[q];
    float u2 = (q < 3) ? ut[q + 4] : 1.f;

    // gate accumulators, init = column kcur of fused [W_ih | bias] table
    float acc[4][8];
#pragma unroll
    for (int s = 0; s < 4; s++)
#pragma unroll
      for (int m = 0; m < 8; m++)
        acc[s][m] = sm[OFF_WIHB + (s * Hh + q + 4 * m) * 8 + kcur];

    // stream h through float4 chunks; per-row k-order unchanged (ascending)
#pragma unroll
    for (int kc = 0; kc < 8; kc++) {
      float4 hv = *(const float4*)&sm[OFF_HBUF + bb * HBUF_S + 4 * kc];
#pragma unroll
      for (int s = 0; s < 4; s++)
#pragma unroll
        for (int m = 0; m < 8; m++) {
          float4 w = *(const float4*)&sm[OFF_WHH + (s * Hh + q + 4 * m) * WHH_S + 4 * kc];
          float a = acc[s][m];
          a = fmaf(w.x, hv.x, a);
          a = fmaf(w.y, hv.y, a);
          a = fmaf(w.z, hv.z, a);
          a = fmaf(w.w, hv.w, a);
          acc[s][m] = a;
        }
    }

    // elementwise LSTM cell
    float hnew[8];
#pragma unroll
    for (int m = 0; m < 8; m++) {
      float ig = 1.f / (1.f + expf(-acc[0][m]));
      float fg = 1.f / (1.f + expf(-acc[1][m]));
      float gg = tanhf(acc[2][m]);
      float og = 1.f / (1.f + expf(-acc[3][m]));
      float cc = fg * c[m] + ig * gg;
      c[m] = cc;
      hnew[m] = og * tanhf(cc);
    }
#pragma unroll
    for (int m = 0; m < 8; m++) sm[OFF_HBUF + bb * HBUF_S + q + 4 * m] = hnew[m];

    // head: partial logits over own slots, quad butterfly-sum (same order)
    float lg[8];
#pragma unroll
    for (int p = 0; p < 8; p++) lg[p] = 0.f;
#pragma unroll
    for (int m = 0; m < 8; m++) {
      float4 w0 = *(const float4*)&sm[OFF_WHEAD + (q + 4 * m) * 8];
      float4 w1 = *(const float4*)&sm[OFF_WHEAD + (q + 4 * m) * 8 + 4];
      lg[0] = fmaf(w0.x, hnew[m], lg[0]);
      lg[1] = fmaf(w0.y, hnew[m], lg[1]);
      lg[2] = fmaf(w0.z, hnew[m], lg[2]);
      lg[3] = fmaf(w0.w, hnew[m], lg[3]);
      lg[4] = fmaf(w1.x, hnew[m], lg[4]);
      lg[5] = fmaf(w1.y, hnew[m], lg[5]);
      lg[6] = fmaf(w1.z, hnew[m], lg[6]);
    }
#pragma unroll
    for (int p = 0; p < Pp; p++) {
      lg[p] += __shfl_xor(lg[p], 1);
      lg[p] += __shfl_xor(lg[p], 2);
      lg[p] += bh[p];
    }

    // gumbel noise + argmax (tie -> lower index)
    float n1 = -logf(-logf(u1 + 1e-20f) + 1e-20f);
    float bestv = lg[q] + n1;
    int besti = q;
    if (q < 3) {
      float n2 = -logf(-logf(u2 + 1e-20f) + 1e-20f);
      float v2 = lg[q + 4] + n2;
      if (v2 > bestv) { bestv = v2; besti = q + 4; }
    }
#pragma unroll
    for (int mask = 1; mask <= 2; mask <<= 1) {
      float ov = __shfl_xor(bestv, mask);
      int   oi = __shfl_xor(besti, mask);
      if (ov > bestv || (ov == bestv && oi < besti)) { bestv = ov; besti = oi; }
    }
    kcur = besti;

    // stage outputs in LDS
    {
      int t8 = (t & 7) * Pp;
      float* sl = &sm[OFF_OUTL + bb * OUT_S + t8];
      float* ss = &sm[OFF_OUTS + bb * OUT_S + t8];
      sl[q] = lg[q];
      ss[q] = (besti == q) ? 1.f : 0.f;
      if (q < 3) {
        sl[q + 4] = lg[q + 4];
        ss[q + 4] = (besti == (q + 4)) ? 1.f : 0.f;
      }
    }

    // flush every 8 steps (coalesced 64B-per-quad float4 stores)
    if ((t & 7) == 7) {
      int t0 = t - 7;
#pragma unroll
      for (int i = 0; i < 4; i++) {
        int idx = q + 4 * i;
        if (idx < 14) {
          float4 vL = *(const float4*)&sm[OFF_OUTL + bb * OUT_S + 4 * idx];
          float4 vS = *(const float4*)&sm[OFF_OUTS + bb * OUT_S + 4 * idx];
          *(float4*)&outL[(size_t)t0 * Pp + 4 * idx] = vL;
          *(float4*)&outS[(size_t)t0 * Pp + 4 * idx] = vS;
        }
      }
    } else if (t == T - 1) {
      // generic tail (T not multiple of 8): scalar flush
      int t0 = t & ~7;
      int cnt = (t - t0 + 1) * Pp;
      for (int i = q; i < cnt; i += 4) {
        outL[(size_t)t0 * Pp + i] = sm[OFF_OUTL + bb * OUT_S + i];
        outS[(size_t)t0 * Pp + i] = sm[OFF_OUTS + bb * OUT_S + i];
      }
    }
  }
}

extern "C" void kernel_launch(void* const* d_in, const int* in_sizes, int n_in,
                              void* d_out, int out_size, void* d_ws, size_t ws_size,
                              hipStream_t stream) {
  const float* h_n     = (const float*)d_in[0];
  const float* c_n     = (const float*)d_in[1];
  const float* noise   = (const float*)d_in[2];
  const float* gumbel  = (const float*)d_in[3];
  const float* W_init  = (const float*)d_in[4];
  const float* b_init  = (const float*)d_in[5];
  const float* W_ih    = (const float*)d_in[6];
  const float* W_hh    = (const float*)d_in[7];
  const float* b_ih    = (const float*)d_in[8];
  const float* b_hh    = (const float*)d_in[9];
  const float* W_head  = (const float*)d_in[10];
  const float* b_head  = (const float*)d_in[11];
  const int*   fut_len = (const int*)d_in[12];

  int B = in_sizes[0] / Hh;  // 32768
  dim3 grid((B + 63) / 64), block(256);
  gen_decoder_kernel<<<grid, block, 0, stream>>>(
      h_n, c_n, noise, gumbel, W_init, b_init, W_ih, W_hh, b_ih, b_hh,
      W_head, b_head, fut_len, (float*)d_out, B);
}